// Round 2
// 224.439 us; speedup vs baseline: 1.0931x; 1.0931x over previous
//
#include <hip/hip_runtime.h>

#define IN_DIM  2048   // K
#define OUT_DIM 2048   // N
#define MROWS   8192   // M = B*S
#define RANK    4
#define BK      64

typedef unsigned short ushort_t;
typedef __attribute__((ext_vector_type(8))) short  short8;   // 8 bf16 (4 VGPRs)
typedef __attribute__((ext_vector_type(4))) float  floatx4;  // MFMA acc

__device__ __forceinline__ unsigned short f2bf(float f) {
  union { float f; unsigned int u; } v; v.f = f;
  unsigned int r = v.u + 0x7fffu + ((v.u >> 16) & 1u);  // RNE
  return (unsigned short)(r >> 16);
}

__device__ __forceinline__ void gload16(const ushort_t* g, short* l) {
  __builtin_amdgcn_global_load_lds(
      (const __attribute__((address_space(1))) void*)g,
      (__attribute__((address_space(3))) void*)l, 16, 0, 0);
}

// ---- kernel 1: rank coefficients c[r] = softplus(mag)/(||A[:,r]|| * ||B[r,:]||) ----
__global__ void coef_kernel(const float* __restrict__ sA, const float* __restrict__ sB,
                            const float* __restrict__ mag, float* __restrict__ cOut) {
  __shared__ float part[8][256];
  __shared__ float tot[8];
  int t = threadIdx.x;
  float sa[4] = {0.f, 0.f, 0.f, 0.f};
  for (int o = t; o < OUT_DIM; o += 256) {
    float4 v = *(const float4*)(sA + o * 4);
    sa[0] += v.x * v.x; sa[1] += v.y * v.y; sa[2] += v.z * v.z; sa[3] += v.w * v.w;
  }
  float sb[4] = {0.f, 0.f, 0.f, 0.f};
  for (int r = 0; r < 4; ++r)
    for (int i = t; i < IN_DIM; i += 256) { float v = sB[r * IN_DIM + i]; sb[r] += v * v; }
  for (int q = 0; q < 4; ++q) { part[q][t] = sa[q]; part[4 + q][t] = sb[q]; }
  __syncthreads();
  if (t < 8) { float s = 0.f; for (int j = 0; j < 256; ++j) s += part[t][j]; tot[t] = s; }
  __syncthreads();
  if (t < 4) {
    float g  = log1pf(expf(mag[t])) + 1e-6f;        // softplus + mag_eps
    float na = fmaxf(sqrtf(tot[t]),     1e-6f);
    float nb = fmaxf(sqrtf(tot[4 + t]), 1e-6f);
    cOut[t] = g / (na * nb);
  }
}

// ---- kernel 2 (fused): blocks [0,8192): cast x->bf16; blocks [8192,10240): build W ----
__global__ void prep_kernel(const float* __restrict__ x, ushort_t* __restrict__ xb,
                            const int* __restrict__ idx, const float* __restrict__ lut,
                            const float* __restrict__ sA, const float* __restrict__ sB,
                            const float* __restrict__ c, ushort_t* __restrict__ W) {
  int t = threadIdx.x;
  if (blockIdx.x < 8192) {
    size_t i = ((size_t)blockIdx.x * 256 + t) * 8;
    float4 a = *(const float4*)(x + i);
    float4 b = *(const float4*)(x + i + 4);
    uint4 o4;
    o4.x = (unsigned)f2bf(a.x) | ((unsigned)f2bf(a.y) << 16);
    o4.y = (unsigned)f2bf(a.z) | ((unsigned)f2bf(a.w) << 16);
    o4.z = (unsigned)f2bf(b.x) | ((unsigned)f2bf(b.y) << 16);
    o4.w = (unsigned)f2bf(b.z) | ((unsigned)f2bf(b.w) << 16);
    *(uint4*)(xb + i) = o4;
  } else {
    __shared__ float aA[4];
    __shared__ float lutS[16];
    int o = blockIdx.x - 8192;
    if (t < 4)  aA[t]   = fabsf(sA[o * 4 + t]) * c[t];
    if (t < 16) lutS[t] = lut[t];
    __syncthreads();
    int i = t * 8;
    const int4* ip4 = (const int4*)(idx + (size_t)o * IN_DIM + i);
    int4 i0 = ip4[0], i1 = ip4[1];
    int ii[8] = {i0.x, i0.y, i0.z, i0.w, i1.x, i1.y, i1.z, i1.w};
    unsigned short u[8];
    #pragma unroll
    for (int j = 0; j < 8; ++j) {
      float s = aA[0] * fabsf(sB[0 * IN_DIM + i + j])
              + aA[1] * fabsf(sB[1 * IN_DIM + i + j])
              + aA[2] * fabsf(sB[2 * IN_DIM + i + j])
              + aA[3] * fabsf(sB[3 * IN_DIM + i + j]);
      u[j] = f2bf(lutS[ii[j]] * s);
    }
    uint4 o4;
    o4.x = (unsigned)u[0] | ((unsigned)u[1] << 16);
    o4.y = (unsigned)u[2] | ((unsigned)u[3] << 16);
    o4.z = (unsigned)u[4] | ((unsigned)u[5] << 16);
    o4.w = (unsigned)u[6] | ((unsigned)u[7] << 16);
    *(uint4*)(W + (size_t)o * IN_DIM + i) = o4;
  }
}

// ============================================================================
// kernel 3: C[M,N] = A[M,K] * W[N,K]^T + bias
// 256x256 tile, BK=64, 8 waves (2x4), 8-phase counted-vmcnt schedule (T2+T3+T4+T5).
// LDS 128 KiB STATIC: buf0{A,B} + buf1{A,B}, each tile 256x64 bf16, rows of 8 16B
// chunks, chunk c of row r stored at slot c^(r&7) (conflict-free ds_read_b128;
// swizzle applied on the per-lane GLOBAL source, LDS dest stays linear for
// global_load_lds).
// Per K-tile: 4 phases by M-quarter (mq). B-frags (8x b128) read at the tile's first
// phase, A-frags (4x b128) per phase, 16 MFMA per phase. One half-tile (2 loads/thr)
// prefetched per phase; vmcnt(6) only at phases 4/8 -> 3 half-tiles stay in flight
// across raw s_barriers (no vmcnt(0) drain in the main loop).
// Stage targets only regions whose last read finished >=1 barrier-pair earlier:
//   tile u+2 -> buf0: P2 Bh0, P3 Bh1, P4 Ah0, P5 Ah1 (A "half" h = rows {h*64..}U{128+h*64..})
//   tile u+3 -> buf1: P6 Bh0, P7 Bh1, P8 Ah0, P1(next) Ah1
// vmcnt(6)@P4 retires prev-iter P6..P8 + P1 -> buf1's tile landed;
// vmcnt(6)@P8 retires P2..P5 -> buf0's next tile landed.
// ============================================================================

#define MFMA16(a, b, c) __builtin_amdgcn_mfma_f32_16x16x32_bf16(a, b, c, 0, 0, 0)

__device__ __forceinline__ void barrier_raw() {
  asm volatile("" ::: "memory");          // IR fence: no memory op crosses
  __builtin_amdgcn_s_barrier();
  asm volatile("" ::: "memory");
}

// stage one A/B half-tile (h) of K-tile `tile` into `ldsbase` (2 x gload16/thread)
__device__ __forceinline__ void stage_half(const ushort_t* gbase, short* ldsbase,
                                           int tile, int h, int wid) {
  gload16(gbase + (size_t)h * 64 * IN_DIM + (size_t)tile * BK,
          ldsbase + (h * 512 + wid * 64) * 8);
  gload16(gbase + ((size_t)h * 64 + 128) * IN_DIM + (size_t)tile * BK,
          ldsbase + (1024 + h * 512 + wid * 64) * 8);
}

template <int MQ, bool FIRST, typename StageFn>
__device__ __forceinline__ void phase(const short* aRd, const short* bRd,
                                      int ko0, int ko1,
                                      floatx4 (&acc)[8][4],
                                      short8 (&bf0)[4], short8 (&bf1)[4],
                                      StageFn&& stage, int vm) {
  if (FIRST) {
    #pragma unroll
    for (int ni = 0; ni < 4; ++ni) {
      bf0[ni] = *(const short8*)(bRd + ni * 1024 + ko0);
      bf1[ni] = *(const short8*)(bRd + ni * 1024 + ko1);
    }
  }
  short8 a0k0 = *(const short8*)(aRd + (2 * MQ) * 1024 + ko0);
  short8 a0k1 = *(const short8*)(aRd + (2 * MQ) * 1024 + ko1);
  short8 a1k0 = *(const short8*)(aRd + (2 * MQ + 1) * 1024 + ko0);
  short8 a1k1 = *(const short8*)(aRd + (2 * MQ + 1) * 1024 + ko1);
  stage();
  if (vm == 6)      asm volatile("s_waitcnt vmcnt(6)" ::: "memory");
  else if (vm == 0) asm volatile("s_waitcnt vmcnt(0)" ::: "memory");
  barrier_raw();
  __builtin_amdgcn_s_setprio(1);
  #pragma unroll
  for (int ni = 0; ni < 4; ++ni) {
    acc[2 * MQ    ][ni] = MFMA16(a0k0, bf0[ni], acc[2 * MQ    ][ni]);
    acc[2 * MQ    ][ni] = MFMA16(a0k1, bf1[ni], acc[2 * MQ    ][ni]);
    acc[2 * MQ + 1][ni] = MFMA16(a1k0, bf0[ni], acc[2 * MQ + 1][ni]);
    acc[2 * MQ + 1][ni] = MFMA16(a1k1, bf1[ni], acc[2 * MQ + 1][ni]);
  }
  __builtin_amdgcn_s_setprio(0);
  barrier_raw();
}

__global__ __launch_bounds__(512, 2) void gemm_kernel(const ushort_t* __restrict__ A,
                                                      const ushort_t* __restrict__ W,
                                                      const float* __restrict__ bias,
                                                      float* __restrict__ C) {
  __shared__ short lA0[16384];   // 256x64 bf16 = 32 KiB each, 128 KiB total
  __shared__ short lB0[16384];
  __shared__ short lA1[16384];
  __shared__ short lB1[16384];

  const int t    = threadIdx.x;
  const int lane = t & 63;
  const int wid  = t >> 6;       // 8 waves: 2 (M) x 4 (N)
  const int wr   = wid >> 2;
  const int wc   = wid & 3;
  const int rowBase = blockIdx.y * 256;
  const int colBase = blockIdx.x * 256;   // bid%8 == blockIdx.x -> per-XCD W panel

  // staging source: thread covers row srcRow of each 64-row quadrant, chunk pre-swizzled
  const int srcRow   = wid * 8 + (lane >> 3);
  const int srcChunk = (lane & 7) ^ (lane >> 3);   // slot ^ (row&7)
  const ushort_t* gA = A + (size_t)(rowBase + srcRow) * IN_DIM + srcChunk * 8;
  const ushort_t* gB = W + (size_t)(colBase + srcRow) * IN_DIM + srcChunk * 8;

  // fragment-read addressing
  const int rA  = lane & 15;
  const int kh  = lane >> 4;
  const int sw  = rA & 7;
  const int ko0 = ((kh)     ^ sw) * 8;   // kk=0 chunk, swizzled, in shorts
  const int ko1 = ((4 + kh) ^ sw) * 8;   // kk=1
  const short* aRd0 = lA0 + (wr * 128 + rA) * 64;
  const short* bRd0 = lB0 + (wc * 64  + rA) * 64;
  const short* aRd1 = lA1 + (wr * 128 + rA) * 64;
  const short* bRd1 = lB1 + (wc * 64  + rA) * 64;

  floatx4 acc[8][4];
  #pragma unroll
  for (int i = 0; i < 8; ++i)
    #pragma unroll
    for (int j = 0; j < 4; ++j) acc[i][j] = (floatx4){0.f, 0.f, 0.f, 0.f};
  short8 bf0[4], bf1[4];

  // prologue: tile0 complete (8 loads), then tile1 Bh0,Bh1,Ah0 (6 loads)
  stage_half(gA, lA0, 0, 0, wid);
  stage_half(gA, lA0, 0, 1, wid);
  stage_half(gB, lB0, 0, 0, wid);
  stage_half(gB, lB0, 0, 1, wid);
  stage_half(gB, lB1, 1, 0, wid);
  stage_half(gB, lB1, 1, 1, wid);
  stage_half(gA, lA1, 1, 0, wid);
  asm volatile("s_waitcnt vmcnt(6)" ::: "memory");   // tile0's 8 loads landed
  barrier_raw();

  #pragma unroll 1
  for (int i = 0; i < 16; ++i) {                     // 2 K-tiles / iter, 32 tiles
    const int  t2   = 2 * i + 2, t3 = 2 * i + 3;
    const bool more = (i < 15);
    // tile 2i from buf0
    phase<0, true >(aRd0, bRd0, ko0, ko1, acc, bf0, bf1,
                    [&] { stage_half(gA, lA1, 2 * i + 1, 1, wid); }, -1);
    phase<1, false>(aRd0, bRd0, ko0, ko1, acc, bf0, bf1,
                    [&] { if (more) stage_half(gB, lB0, t2, 0, wid); }, -1);
    phase<2, false>(aRd0, bRd0, ko0, ko1, acc, bf0, bf1,
                    [&] { if (more) stage_half(gB, lB0, t2, 1, wid); }, -1);
    phase<3, false>(aRd0, bRd0, ko0, ko1, acc, bf0, bf1,
                    [&] { if (more) stage_half(gA, lA0, t2, 0, wid); }, more ? 6 : 0);
    // tile 2i+1 from buf1
    phase<0, true >(aRd1, bRd1, ko0, ko1, acc, bf0, bf1,
                    [&] { if (more) stage_half(gA, lA0, t2, 1, wid); }, -1);
    phase<1, false>(aRd1, bRd1, ko0, ko1, acc, bf0, bf1,
                    [&] { if (more) stage_half(gB, lB1, t3, 0, wid); }, -1);
    phase<2, false>(aRd1, bRd1, ko0, ko1, acc, bf0, bf1,
                    [&] { if (more) stage_half(gB, lB1, t3, 1, wid); }, -1);
    phase<3, false>(aRd1, bRd1, ko0, ko1, acc, bf0, bf1,
                    [&] { if (more) stage_half(gA, lA1, t3, 0, wid); }, more ? 6 : -1);
  }

  // epilogue: D col = lane&15, row = (lane>>4)*4 + reg
  const int mB = rowBase + wr * 128 + (lane >> 4) * 4;
  const int nB = colBase + wc * 64 + (lane & 15);
  #pragma unroll
  for (int ni = 0; ni < 4; ++ni) {
    float bv = bias[nB + ni * 16];
    #pragma unroll
    for (int mi = 0; mi < 8; ++mi)
      #pragma unroll
      for (int r = 0; r < 4; ++r)
        C[(size_t)(mB + mi * 16 + r) * OUT_DIM + (nB + ni * 16)] = acc[mi][ni][r] + bv;
  }
}

extern "C" void kernel_launch(void* const* d_in, const int* in_sizes, int n_in,
                              void* d_out, int out_size, void* d_ws, size_t ws_size,
                              hipStream_t stream) {
  const float* x    = (const float*)d_in[0];
  const int*   idx  = (const int*)d_in[1];
  const float* lut  = (const float*)d_in[2];
  const float* sA   = (const float*)d_in[3];
  const float* sB   = (const float*)d_in[4];
  const float* mag  = (const float*)d_in[5];
  const float* bias = (const float*)d_in[6];
  float* y = (float*)d_out;

  char* ws = (char*)d_ws;
  float*    c  = (float*)ws;                                            // 16 B
  ushort_t* W  = (ushort_t*)(ws + 256);                                 // 8 MiB
  ushort_t* xb = (ushort_t*)(ws + 256 + (size_t)OUT_DIM * IN_DIM * 2);  // 32 MiB

  coef_kernel<<<1, 256, 0, stream>>>(sA, sB, mag, c);
  prep_kernel<<<8192 + OUT_DIM, 256, 0, stream>>>(x, xb, idx, lut, sA, sB, c, W);
  dim3 g(OUT_DIM / 256, MROWS / 256);
  gemm_kernel<<<g, 512, 0, stream>>>(xb, W, bias, y);
}

// Round 3
// 218.128 us; speedup vs baseline: 1.1247x; 1.0289x over previous
//
#include <hip/hip_runtime.h>

#define IN_DIM  2048   // K
#define OUT_DIM 2048   // N
#define MROWS   8192   // M = B*S
#define RANK    4
#define BK      64

typedef unsigned short ushort_t;
typedef __attribute__((ext_vector_type(8))) short  short8;   // 8 bf16 (4 VGPRs)
typedef __attribute__((ext_vector_type(4))) float  floatx4;  // MFMA acc

__device__ __forceinline__ unsigned short f2bf(float f) {
  union { float f; unsigned int u; } v; v.f = f;
  unsigned int r = v.u + 0x7fffu + ((v.u >> 16) & 1u);  // RNE
  return (unsigned short)(r >> 16);
}

__device__ __forceinline__ void gload16(const ushort_t* g, short* l) {
  __builtin_amdgcn_global_load_lds(
      (const __attribute__((address_space(1))) void*)g,
      (__attribute__((address_space(3))) void*)l, 16, 0, 0);
}

// ---- kernel 1: rank coefficients c[r] = softplus(mag)/(||A[:,r]|| * ||B[r,:]||) ----
__global__ void coef_kernel(const float* __restrict__ sA, const float* __restrict__ sB,
                            const float* __restrict__ mag, float* __restrict__ cOut) {
  __shared__ float part[8][256];
  __shared__ float tot[8];
  int t = threadIdx.x;
  float sa[4] = {0.f, 0.f, 0.f, 0.f};
  for (int o = t; o < OUT_DIM; o += 256) {
    float4 v = *(const float4*)(sA + o * 4);
    sa[0] += v.x * v.x; sa[1] += v.y * v.y; sa[2] += v.z * v.z; sa[3] += v.w * v.w;
  }
  float sb[4] = {0.f, 0.f, 0.f, 0.f};
  for (int r = 0; r < 4; ++r)
    for (int i = t; i < IN_DIM; i += 256) { float v = sB[r * IN_DIM + i]; sb[r] += v * v; }
  for (int q = 0; q < 4; ++q) { part[q][t] = sa[q]; part[4 + q][t] = sb[q]; }
  __syncthreads();
  if (t < 8) { float s = 0.f; for (int j = 0; j < 256; ++j) s += part[t][j]; tot[t] = s; }
  __syncthreads();
  if (t < 4) {
    float g  = log1pf(expf(mag[t])) + 1e-6f;        // softplus + mag_eps
    float na = fmaxf(sqrtf(tot[t]),     1e-6f);
    float nb = fmaxf(sqrtf(tot[4 + t]), 1e-6f);
    cOut[t] = g / (na * nb);
  }
}

// ---- kernel 2 (fused): blocks [0,8192): cast x->bf16; blocks [8192,10240): build W ----
__global__ void prep_kernel(const float* __restrict__ x, ushort_t* __restrict__ xb,
                            const int* __restrict__ idx, const float* __restrict__ lut,
                            const float* __restrict__ sA, const float* __restrict__ sB,
                            const float* __restrict__ c, ushort_t* __restrict__ W) {
  int t = threadIdx.x;
  if (blockIdx.x < 8192) {
    size_t i = ((size_t)blockIdx.x * 256 + t) * 8;
    float4 a = *(const float4*)(x + i);
    float4 b = *(const float4*)(x + i + 4);
    uint4 o4;
    o4.x = (unsigned)f2bf(a.x) | ((unsigned)f2bf(a.y) << 16);
    o4.y = (unsigned)f2bf(a.z) | ((unsigned)f2bf(a.w) << 16);
    o4.z = (unsigned)f2bf(b.x) | ((unsigned)f2bf(b.y) << 16);
    o4.w = (unsigned)f2bf(b.z) | ((unsigned)f2bf(b.w) << 16);
    *(uint4*)(xb + i) = o4;
  } else {
    __shared__ float aA[4];
    __shared__ float lutS[16];
    int o = blockIdx.x - 8192;
    if (t < 4)  aA[t]   = fabsf(sA[o * 4 + t]) * c[t];
    if (t < 16) lutS[t] = lut[t];
    __syncthreads();
    int i = t * 8;
    const int4* ip4 = (const int4*)(idx + (size_t)o * IN_DIM + i);
    int4 i0 = ip4[0], i1 = ip4[1];
    int ii[8] = {i0.x, i0.y, i0.z, i0.w, i1.x, i1.y, i1.z, i1.w};
    unsigned short u[8];
    #pragma unroll
    for (int j = 0; j < 8; ++j) {
      float s = aA[0] * fabsf(sB[0 * IN_DIM + i + j])
              + aA[1] * fabsf(sB[1 * IN_DIM + i + j])
              + aA[2] * fabsf(sB[2 * IN_DIM + i + j])
              + aA[3] * fabsf(sB[3 * IN_DIM + i + j]);
      u[j] = f2bf(lutS[ii[j]] * s);
    }
    uint4 o4;
    o4.x = (unsigned)u[0] | ((unsigned)u[1] << 16);
    o4.y = (unsigned)u[2] | ((unsigned)u[3] << 16);
    o4.z = (unsigned)u[4] | ((unsigned)u[5] << 16);
    o4.w = (unsigned)u[6] | ((unsigned)u[7] << 16);
    *(uint4*)(W + (size_t)o * IN_DIM + i) = o4;
  }
}

// ============================================================================
// kernel 3: C[M,N] = A[M,K] * W[N,K]^T + bias
// 256x256 tile, BK=64, 8 waves (2x4), 8-phase counted-vmcnt schedule (T2+T3+T4+T5).
// LDS 128 KiB STATIC: buf0{A,B} + buf1{A,B}, each tile 256x64 bf16, rows of 8 16B
// chunks, chunk c of row r stored at slot c^(r&7) (conflict-free ds_read_b128;
// swizzle applied on the per-lane GLOBAL source, LDS dest stays linear for
// global_load_lds).
// Per K-tile: 4 phases by M-quarter (mq). B-frags (8x b128) read at the tile's first
// phase, A-frags (4x b128) per phase, 16 MFMA per phase. One half-tile (2 loads/thr)
// prefetched per phase; vmcnt(6) only at phases 4/8 -> 3 half-tiles stay in flight
// across raw s_barriers (no vmcnt(0) drain in the main loop).
// Stage targets only regions whose last read finished >=1 barrier-pair earlier:
//   tile u+2 -> buf0: P2 Bh0, P3 Bh1, P4 Ah0, P5 Ah1 (A "half" h = rows {h*64..}U{128+h*64..})
//   tile u+3 -> buf1: P6 Bh0, P7 Bh1, P8 Ah0, P1(next) Ah1
// vmcnt(6)@P4 retires prev-iter P6..P8 + P1 -> buf1's tile landed;
// vmcnt(6)@P8 retires P2..P5 -> buf0's next tile landed.
//
// R2 change: XCD-chunked tile remap. HW assigns XCD = flat_bid % 8 (round-robin);
// previously that made each XCD read ALL of A (32 MiB) with zero intra-XCD reuse
// (FETCH 135 MB vs 40 ideal; staging-service ~11 B/cyc/CU). Now each XCD owns an
// 8(y) x 4(x) chunk of the 32x8 tile grid: per-XCD unique bytes A 8 MiB + W 4 MiB,
// A reused 4x / W 8x inside the XCD's L2. Bijective: flat=(y*8+x) <-> (xcd,slot)
// <-> (tileY,tileX).
// ============================================================================

#define MFMA16(a, b, c) __builtin_amdgcn_mfma_f32_16x16x32_bf16(a, b, c, 0, 0, 0)

__device__ __forceinline__ void barrier_raw() {
  asm volatile("" ::: "memory");          // IR fence: no memory op crosses
  __builtin_amdgcn_s_barrier();
  asm volatile("" ::: "memory");
}

// stage one A/B half-tile (h) of K-tile `tile` into `ldsbase` (2 x gload16/thread)
__device__ __forceinline__ void stage_half(const ushort_t* gbase, short* ldsbase,
                                           int tile, int h, int wid) {
  gload16(gbase + (size_t)h * 64 * IN_DIM + (size_t)tile * BK,
          ldsbase + (h * 512 + wid * 64) * 8);
  gload16(gbase + ((size_t)h * 64 + 128) * IN_DIM + (size_t)tile * BK,
          ldsbase + (1024 + h * 512 + wid * 64) * 8);
}

template <int MQ, bool FIRST, typename StageFn>
__device__ __forceinline__ void phase(const short* aRd, const short* bRd,
                                      int ko0, int ko1,
                                      floatx4 (&acc)[8][4],
                                      short8 (&bf0)[4], short8 (&bf1)[4],
                                      StageFn&& stage, int vm) {
  if (FIRST) {
    #pragma unroll
    for (int ni = 0; ni < 4; ++ni) {
      bf0[ni] = *(const short8*)(bRd + ni * 1024 + ko0);
      bf1[ni] = *(const short8*)(bRd + ni * 1024 + ko1);
    }
  }
  short8 a0k0 = *(const short8*)(aRd + (2 * MQ) * 1024 + ko0);
  short8 a0k1 = *(const short8*)(aRd + (2 * MQ) * 1024 + ko1);
  short8 a1k0 = *(const short8*)(aRd + (2 * MQ + 1) * 1024 + ko0);
  short8 a1k1 = *(const short8*)(aRd + (2 * MQ + 1) * 1024 + ko1);
  stage();
  if (vm == 6)      asm volatile("s_waitcnt vmcnt(6)" ::: "memory");
  else if (vm == 0) asm volatile("s_waitcnt vmcnt(0)" ::: "memory");
  barrier_raw();
  __builtin_amdgcn_s_setprio(1);
  #pragma unroll
  for (int ni = 0; ni < 4; ++ni) {
    acc[2 * MQ    ][ni] = MFMA16(a0k0, bf0[ni], acc[2 * MQ    ][ni]);
    acc[2 * MQ    ][ni] = MFMA16(a0k1, bf1[ni], acc[2 * MQ    ][ni]);
    acc[2 * MQ + 1][ni] = MFMA16(a1k0, bf0[ni], acc[2 * MQ + 1][ni]);
    acc[2 * MQ + 1][ni] = MFMA16(a1k1, bf1[ni], acc[2 * MQ + 1][ni]);
  }
  __builtin_amdgcn_s_setprio(0);
  barrier_raw();
}

__global__ __launch_bounds__(512, 2) void gemm_kernel(const ushort_t* __restrict__ A,
                                                      const ushort_t* __restrict__ W,
                                                      const float* __restrict__ bias,
                                                      float* __restrict__ C) {
  __shared__ short lA0[16384];   // 256x64 bf16 = 32 KiB each, 128 KiB total
  __shared__ short lB0[16384];
  __shared__ short lA1[16384];
  __shared__ short lB1[16384];

  const int t    = threadIdx.x;
  const int lane = t & 63;
  const int wid  = t >> 6;       // 8 waves: 2 (M) x 4 (N)
  const int wr   = wid >> 2;
  const int wc   = wid & 3;

  // XCD-chunked tile remap (see header comment). flat id in hw dispatch order:
  const int flat  = blockIdx.y * 8 + blockIdx.x;   // x-fastest
  const int xcd   = flat & 7;                      // round-robin XCD assignment
  const int slot  = flat >> 3;                     // 0..31: CU slot within XCD
  const int tileY = (xcd >> 1) * 8 + (slot >> 2);  // 8 consecutive y-tiles / XCD
  const int tileX = (xcd & 1) * 4 + (slot & 3);    // 4 consecutive x-tiles / XCD
  const int rowBase = tileY * 256;
  const int colBase = tileX * 256;

  // staging source: thread covers row srcRow of each 64-row quadrant, chunk pre-swizzled
  const int srcRow   = wid * 8 + (lane >> 3);
  const int srcChunk = (lane & 7) ^ (lane >> 3);   // slot ^ (row&7)
  const ushort_t* gA = A + (size_t)(rowBase + srcRow) * IN_DIM + srcChunk * 8;
  const ushort_t* gB = W + (size_t)(colBase + srcRow) * IN_DIM + srcChunk * 8;

  // fragment-read addressing
  const int rA  = lane & 15;
  const int kh  = lane >> 4;
  const int sw  = rA & 7;
  const int ko0 = ((kh)     ^ sw) * 8;   // kk=0 chunk, swizzled, in shorts
  const int ko1 = ((4 + kh) ^ sw) * 8;   // kk=1
  const short* aRd0 = lA0 + (wr * 128 + rA) * 64;
  const short* bRd0 = lB0 + (wc * 64  + rA) * 64;
  const short* aRd1 = lA1 + (wr * 128 + rA) * 64;
  const short* bRd1 = lB1 + (wc * 64  + rA) * 64;

  floatx4 acc[8][4];
  #pragma unroll
  for (int i = 0; i < 8; ++i)
    #pragma unroll
    for (int j = 0; j < 4; ++j) acc[i][j] = (floatx4){0.f, 0.f, 0.f, 0.f};
  short8 bf0[4], bf1[4];

  // prologue: tile0 complete (8 loads), then tile1 Bh0,Bh1,Ah0 (6 loads)
  stage_half(gA, lA0, 0, 0, wid);
  stage_half(gA, lA0, 0, 1, wid);
  stage_half(gB, lB0, 0, 0, wid);
  stage_half(gB, lB0, 0, 1, wid);
  stage_half(gB, lB1, 1, 0, wid);
  stage_half(gB, lB1, 1, 1, wid);
  stage_half(gA, lA1, 1, 0, wid);
  asm volatile("s_waitcnt vmcnt(6)" ::: "memory");   // tile0's 8 loads landed
  barrier_raw();

  #pragma unroll 1
  for (int i = 0; i < 16; ++i) {                     // 2 K-tiles / iter, 32 tiles
    const int  t2   = 2 * i + 2, t3 = 2 * i + 3;
    const bool more = (i < 15);
    // tile 2i from buf0
    phase<0, true >(aRd0, bRd0, ko0, ko1, acc, bf0, bf1,
                    [&] { stage_half(gA, lA1, 2 * i + 1, 1, wid); }, -1);
    phase<1, false>(aRd0, bRd0, ko0, ko1, acc, bf0, bf1,
                    [&] { if (more) stage_half(gB, lB0, t2, 0, wid); }, -1);
    phase<2, false>(aRd0, bRd0, ko0, ko1, acc, bf0, bf1,
                    [&] { if (more) stage_half(gB, lB0, t2, 1, wid); }, -1);
    phase<3, false>(aRd0, bRd0, ko0, ko1, acc, bf0, bf1,
                    [&] { if (more) stage_half(gA, lA0, t2, 0, wid); }, more ? 6 : 0);
    // tile 2i+1 from buf1
    phase<0, true >(aRd1, bRd1, ko0, ko1, acc, bf0, bf1,
                    [&] { if (more) stage_half(gA, lA0, t2, 1, wid); }, -1);
    phase<1, false>(aRd1, bRd1, ko0, ko1, acc, bf0, bf1,
                    [&] { if (more) stage_half(gB, lB1, t3, 0, wid); }, -1);
    phase<2, false>(aRd1, bRd1, ko0, ko1, acc, bf0, bf1,
                    [&] { if (more) stage_half(gB, lB1, t3, 1, wid); }, -1);
    phase<3, false>(aRd1, bRd1, ko0, ko1, acc, bf0, bf1,
                    [&] { if (more) stage_half(gA, lA1, t3, 0, wid); }, more ? 6 : -1);
  }

  // epilogue: D col = lane&15, row = (lane>>4)*4 + reg
  const int mB = rowBase + wr * 128 + (lane >> 4) * 4;
  const int nB = colBase + wc * 64 + (lane & 15);
  #pragma unroll
  for (int ni = 0; ni < 4; ++ni) {
    float bv = bias[nB + ni * 16];
    #pragma unroll
    for (int mi = 0; mi < 8; ++mi)
      #pragma unroll
      for (int r = 0; r < 4; ++r)
        C[(size_t)(mB + mi * 16 + r) * OUT_DIM + (nB + ni * 16)] = acc[mi][ni][r] + bv;
  }
}

extern "C" void kernel_launch(void* const* d_in, const int* in_sizes, int n_in,
                              void* d_out, int out_size, void* d_ws, size_t ws_size,
                              hipStream_t stream) {
  const float* x    = (const float*)d_in[0];
  const int*   idx  = (const int*)d_in[1];
  const float* lut  = (const float*)d_in[2];
  const float* sA   = (const float*)d_in[3];
  const float* sB   = (const float*)d_in[4];
  const float* mag  = (const float*)d_in[5];
  const float* bias = (const float*)d_in[6];
  float* y = (float*)d_out;

  char* ws = (char*)d_ws;
  float*    c  = (float*)ws;                                            // 16 B
  ushort_t* W  = (ushort_t*)(ws + 256);                                 // 8 MiB
  ushort_t* xb = (ushort_t*)(ws + 256 + (size_t)OUT_DIM * IN_DIM * 2);  // 32 MiB

  coef_kernel<<<1, 256, 0, stream>>>(sA, sB, mag, c);
  prep_kernel<<<8192 + OUT_DIM, 256, 0, stream>>>(x, xb, idx, lut, sA, sB, c, W);
  dim3 g(OUT_DIM / 256, MROWS / 256);
  gemm_kernel<<<g, 512, 0, stream>>>(xb, W, bias, y);
}